// Round 18
// baseline (222.119 us; speedup 1.0000x reference)
//
#include <hip/hip_runtime.h>
#include <hip/hip_bf16.h>
#include <type_traits>

#define C_DIM 256
#define NHEAD 8
#define HDIM 32
#define NLVL 4
#define NPT 4
#define DFF_DIM 1024
#define BB 8
#define NQ_DIM 900
#define LEN_DIM 13294
#define ROWS (BB * NQ_DIM)      // 7200
#define VROWS (BB * LEN_DIM)    // 106352
#define VT_LD 928               // padded stride for vT rows (29*32)

typedef __attribute__((ext_vector_type(8))) short short8v;
typedef __attribute__((ext_vector_type(8))) unsigned short ushort8v;
typedef __attribute__((ext_vector_type(4))) float float4v;
typedef __attribute__((ext_vector_type(4))) unsigned short ushort4v;

__device__ __forceinline__ float bf2f(unsigned short u) {
  union { unsigned int i; float f; } v; v.i = ((unsigned int)u) << 16; return v.f;
}
__device__ __forceinline__ unsigned short f2bf(float f) {
  __hip_bfloat16 h = __float2bfloat16(f);
  return *reinterpret_cast<unsigned short*>(&h);
}

// ---------------- merged: weight transpose+convert AND tgt/x0 bf16 prep ----------------
#define WCONV_BLOCKS 2048
__global__ __launch_bounds__(256) void wprep_kernel(
    const float* __restrict__ w0, const float* __restrict__ w1,
    const float* __restrict__ w2, const float* __restrict__ w3,
    const float* __restrict__ w4, const float* __restrict__ w5,
    const float* __restrict__ w6, const float* __restrict__ w7,
    unsigned short* __restrict__ out,
    const float* __restrict__ tgt, const float* __restrict__ qpos,
    unsigned short* __restrict__ tgtbf, unsigned short* __restrict__ x0bf, int n4) {
  int bid = blockIdx.x;
  if (bid < WCONV_BLOCKS) {
    const int Ks[8] = {256, 256, 256, 256, 256, 256, 256, 1024};
    const int Ns[8] = {768, 256, 256, 128, 256, 256, 1024, 256};
    const int Oo[8] = {0, 196608, 262144, 327680, 360448, 425984, 491520, 753664};
    int w = bid >> 8, bx = bid & 255;
    int K = Ks[w], N = Ns[w];
    int ntx = N >> 5, nty = K >> 5;
    if (bx >= ntx * nty) return;
    int tx = bx % ntx, ty = bx / ntx;
    const float* W = w == 0 ? w0 : w == 1 ? w1 : w == 2 ? w2 : w == 3 ? w3
                   : w == 4 ? w4 : w == 5 ? w5 : w == 6 ? w6 : w7;
    __shared__ float tile[32][33];
    int c = threadIdx.x & 31, rg = threadIdx.x >> 5;
#pragma unroll
    for (int j = 0; j < 4; ++j) {
      int k = ty * 32 + rg * 4 + j;
      tile[rg * 4 + j][c] = W[(size_t)k * N + tx * 32 + c];
    }
    __syncthreads();
    unsigned short* o = out + Oo[w];
#pragma unroll
    for (int j = 0; j < 4; ++j) {
      int n = tx * 32 + rg * 4 + j;
      o[(size_t)n * K + ty * 32 + c] = f2bf(tile[c][rg * 4 + j]);
    }
  } else {
    int i = (bid - WCONV_BLOCKS) * 256 + threadIdx.x;
    if (i < n4) {
      float4 x = reinterpret_cast<const float4*>(tgt)[i];
      float4 y = reinterpret_cast<const float4*>(qpos)[i];
      ushort4v u1, u2;
      u1[0] = f2bf(x.x); u1[1] = f2bf(x.y); u1[2] = f2bf(x.z); u1[3] = f2bf(x.w);
      u2[0] = f2bf(x.x + y.x); u2[1] = f2bf(x.y + y.y);
      u2[2] = f2bf(x.z + y.z); u2[3] = f2bf(x.w + y.w);
      *reinterpret_cast<ushort4v*>(tgtbf + (size_t)i * 4) = u1;
      *reinterpret_cast<ushort4v*>(x0bf + (size_t)i * 4) = u2;
    }
  }
}

// ---------------- GEMM body 128x128, BK=64, XOR-swizzled LDS ----------------
template <typename TA, typename TO, int RELU>
__device__ __forceinline__ void gemm_body(
    char* smem,  // 65536 bytes
    const TA* __restrict__ A, const TA* __restrict__ A2,
    const unsigned short* __restrict__ Wt,
    const float* __restrict__ bias, const float* __restrict__ bias2,
    TO* __restrict__ Cout, TO* __restrict__ Cout2,
    int M, int N, int K, int lda, int ldc, int ldc2, int colSplit,
    int bx, int by) {
  const int tid = threadIdx.x;
  const int lane = tid & 63, wid = tid >> 6;
  const int g = lane >> 4, ql = lane & 15;
  const int wr = wid >> 1, wc = wid & 1;
  const int row0 = by * 128, col0 = bx * 128;

  const TA* Ause = (A2 != nullptr && col0 >= colSplit) ? A2 : A;

  float4v acc[4][4];
#pragma unroll
  for (int i = 0; i < 4; ++i)
#pragma unroll
    for (int j = 0; j < 4; ++j) acc[i][j] = (float4v){0.f, 0.f, 0.f, 0.f};

  float4 areg_f[8];
  ushort8v areg_b[4];
  ushort8v wreg[4];

  auto loadA = [&](int k0) {
    if constexpr (std::is_same<TA, float>::value) {
#pragma unroll
      for (int j = 0; j < 8; ++j) {
        int c = tid + 256 * j;
        int row = c >> 4, ch = c & 15;
        int gr = min(row0 + row, M - 1);
        areg_f[j] = *reinterpret_cast<const float4*>(Ause + (size_t)gr * lda + k0 + ch * 4);
      }
    } else {
#pragma unroll
      for (int j = 0; j < 4; ++j) {
        int c = tid + 256 * j;
        int row = c >> 3, ch = c & 7;
        int gr = min(row0 + row, M - 1);
        areg_b[j] = *reinterpret_cast<const ushort8v*>(
            reinterpret_cast<const unsigned short*>(Ause) + (size_t)gr * lda + k0 + ch * 8);
      }
    }
  };
  auto loadW = [&](int k0) {
#pragma unroll
    for (int j = 0; j < 4; ++j) {
      int c = tid + 256 * j;
      int row = c >> 3, ch = c & 7;
      wreg[j] = *reinterpret_cast<const ushort8v*>(
          Wt + (size_t)(col0 + row) * K + k0 + ch * 8);
    }
  };
  auto storeA = [&](int buf) {
    char* base = smem + buf * 16384;
    if constexpr (std::is_same<TA, float>::value) {
#pragma unroll
      for (int j = 0; j < 8; ++j) {
        int c = tid + 256 * j;
        int row = c >> 4, ch = c & 15;
        ushort4v u;
        u[0] = f2bf(areg_f[j].x); u[1] = f2bf(areg_f[j].y);
        u[2] = f2bf(areg_f[j].z); u[3] = f2bf(areg_f[j].w);
        int off = row * 128 + ((ch * 8) ^ ((row & 7) << 4));
        *reinterpret_cast<ushort4v*>(base + off) = u;
      }
    } else {
#pragma unroll
      for (int j = 0; j < 4; ++j) {
        int c = tid + 256 * j;
        int row = c >> 3, ch = c & 7;
        int off = row * 128 + ((ch * 16) ^ ((row & 7) << 4));
        *reinterpret_cast<ushort8v*>(base + off) = areg_b[j];
      }
    }
  };
  auto storeW = [&](int buf) {
    char* base = smem + 32768 + buf * 16384;
#pragma unroll
    for (int j = 0; j < 4; ++j) {
      int c = tid + 256 * j;
      int row = c >> 3, ch = c & 7;
      int off = row * 128 + ((ch * 16) ^ ((row & 7) << 4));
      *reinterpret_cast<ushort8v*>(base + off) = wreg[j];
    }
  };
  auto compute = [&](int buf) {
    const char* abase = smem + buf * 16384;
    const char* wbase = smem + 32768 + buf * 16384;
#pragma unroll
    for (int kk = 0; kk < 2; ++kk) {
      short8v af[4], bfr[4];
#pragma unroll
      for (int mi = 0; mi < 4; ++mi) {
        int r = wr * 64 + mi * 16 + ql;
        int off = r * 128 + ((kk * 64 + g * 16) ^ ((r & 7) << 4));
        af[mi] = *reinterpret_cast<const short8v*>(abase + off);
      }
#pragma unroll
      for (int ni = 0; ni < 4; ++ni) {
        int r = wc * 64 + ni * 16 + ql;
        int off = r * 128 + ((kk * 64 + g * 16) ^ ((r & 7) << 4));
        bfr[ni] = *reinterpret_cast<const short8v*>(wbase + off);
      }
#pragma unroll
      for (int mi = 0; mi < 4; ++mi)
#pragma unroll
        for (int ni = 0; ni < 4; ++ni)
          acc[mi][ni] = __builtin_amdgcn_mfma_f32_16x16x32_bf16(af[mi], bfr[ni], acc[mi][ni], 0, 0, 0);
    }
  };

  const int nt = K >> 6;   // BK = 64
  loadA(0); loadW(0);
  storeA(0); storeW(0);

  for (int t = 0; t < nt; ++t) {
    __syncthreads();
    if (t + 1 < nt) { loadA((t + 1) << 6); loadW((t + 1) << 6); }
    compute(t & 1);
    if (t + 1 < nt) { storeA((t & 1) ^ 1); storeW((t & 1) ^ 1); }
  }

  const bool sel2 = (Cout2 != nullptr && col0 >= colSplit);
  const float* bsrc = sel2 ? bias2 : bias;
  TO* outp = sel2 ? Cout2 : Cout;
  const int ldco = sel2 ? ldc2 : ldc;
  const int cbase = sel2 ? (col0 - colSplit) : col0;
  float bv[4];
#pragma unroll
  for (int ni = 0; ni < 4; ++ni) bv[ni] = bsrc[cbase + wc * 64 + ni * 16 + ql];
#pragma unroll
  for (int mi = 0; mi < 4; ++mi) {
#pragma unroll
    for (int r = 0; r < 4; ++r) {
      int row = row0 + wr * 64 + mi * 16 + 4 * g + r;
      if (row >= M) continue;
#pragma unroll
      for (int ni = 0; ni < 4; ++ni) {
        int col = cbase + wc * 64 + ni * 16 + ql;
        float v = acc[mi][ni][r] + bv[ni];
        if (RELU) v = fmaxf(v, 0.f);
        if constexpr (std::is_same<TO, float>::value) {
          outp[(size_t)row * ldco + col] = v;
        } else {
          outp[(size_t)row * ldco + col] = __float2bfloat16(v);
        }
      }
    }
  }
}

// ---------------- GEMM body 64x64, BK=64, XOR-swizzled LDS ----------------
template <typename TA, typename TO, int RELU>
__device__ __forceinline__ void gemm_body64(
    char* smem,  // 32768 bytes
    const TA* __restrict__ A, const TA* __restrict__ A2,
    const unsigned short* __restrict__ Wt,
    const float* __restrict__ bias, const float* __restrict__ bias2,
    TO* __restrict__ Cout, TO* __restrict__ Cout2,
    int M, int N, int K, int lda, int ldc, int ldc2, int colSplit,
    int bx, int by) {
  const int tid = threadIdx.x;
  const int lane = tid & 63, wid = tid >> 6;
  const int g = lane >> 4, ql = lane & 15;
  const int wr = wid >> 1, wc = wid & 1;
  const int row0 = by * 64, col0 = bx * 64;

  const TA* Ause = (A2 != nullptr && col0 >= colSplit) ? A2 : A;

  float4v acc[2][2];
#pragma unroll
  for (int i = 0; i < 2; ++i)
#pragma unroll
    for (int j = 0; j < 2; ++j) acc[i][j] = (float4v){0.f, 0.f, 0.f, 0.f};

  float4 areg_f[4];
  ushort8v areg_b[2];
  ushort8v wreg[2];

  auto loadA = [&](int k0) {
    if constexpr (std::is_same<TA, float>::value) {
#pragma unroll
      for (int j = 0; j < 4; ++j) {
        int c = tid + 256 * j;
        int row = c >> 4, ch = c & 15;
        int gr = min(row0 + row, M - 1);
        areg_f[j] = *reinterpret_cast<const float4*>(Ause + (size_t)gr * lda + k0 + ch * 4);
      }
    } else {
#pragma unroll
      for (int j = 0; j < 2; ++j) {
        int c = tid + 256 * j;
        int row = c >> 3, ch = c & 7;
        int gr = min(row0 + row, M - 1);
        areg_b[j] = *reinterpret_cast<const ushort8v*>(
            reinterpret_cast<const unsigned short*>(Ause) + (size_t)gr * lda + k0 + ch * 8);
      }
    }
  };
  auto loadW = [&](int k0) {
#pragma unroll
    for (int j = 0; j < 2; ++j) {
      int c = tid + 256 * j;
      int row = c >> 3, ch = c & 7;
      wreg[j] = *reinterpret_cast<const ushort8v*>(
          Wt + (size_t)(col0 + row) * K + k0 + ch * 8);
    }
  };
  auto storeA = [&](int buf) {
    char* base = smem + buf * 8192;
    if constexpr (std::is_same<TA, float>::value) {
#pragma unroll
      for (int j = 0; j < 4; ++j) {
        int c = tid + 256 * j;
        int row = c >> 4, ch = c & 15;
        ushort4v u;
        u[0] = f2bf(areg_f[j].x); u[1] = f2bf(areg_f[j].y);
        u[2] = f2bf(areg_f[j].z); u[3] = f2bf(areg_f[j].w);
        int off = row * 128 + ((ch * 8) ^ ((row & 7) << 4));
        *reinterpret_cast<ushort4v*>(base + off) = u;
      }
    } else {
#pragma unroll
      for (int j = 0; j < 2; ++j) {
        int c = tid + 256 * j;
        int row = c >> 3, ch = c & 7;
        int off = row * 128 + ((ch * 16) ^ ((row & 7) << 4));
        *reinterpret_cast<ushort8v*>(base + off) = areg_b[j];
      }
    }
  };
  auto storeW = [&](int buf) {
    char* base = smem + 16384 + buf * 8192;
#pragma unroll
    for (int j = 0; j < 2; ++j) {
      int c = tid + 256 * j;
      int row = c >> 3, ch = c & 7;
      int off = row * 128 + ((ch * 16) ^ ((row & 7) << 4));
      *reinterpret_cast<ushort8v*>(base + off) = wreg[j];
    }
  };
  auto compute = [&](int buf) {
    const char* abase = smem + buf * 8192;
    const char* wbase = smem + 16384 + buf * 8192;
#pragma unroll
    for (int kk = 0; kk < 2; ++kk) {
      short8v af[2], bfr[2];
#pragma unroll
      for (int mi = 0; mi < 2; ++mi) {
        int r = wr * 32 + mi * 16 + ql;
        int off = r * 128 + ((kk * 64 + g * 16) ^ ((r & 7) << 4));
        af[mi] = *reinterpret_cast<const short8v*>(abase + off);
      }
#pragma unroll
      for (int ni = 0; ni < 2; ++ni) {
        int r = wc * 32 + ni * 16 + ql;
        int off = r * 128 + ((kk * 64 + g * 16) ^ ((r & 7) << 4));
        bfr[ni] = *reinterpret_cast<const short8v*>(wbase + off);
      }
#pragma unroll
      for (int mi = 0; mi < 2; ++mi)
#pragma unroll
        for (int ni = 0; ni < 2; ++ni)
          acc[mi][ni] = __builtin_amdgcn_mfma_f32_16x16x32_bf16(af[mi], bfr[ni], acc[mi][ni], 0, 0, 0);
    }
  };

  const int nt = K >> 6;
  loadA(0); loadW(0);
  storeA(0); storeW(0);

  for (int t = 0; t < nt; ++t) {
    __syncthreads();
    if (t + 1 < nt) { loadA((t + 1) << 6); loadW((t + 1) << 6); }
    compute(t & 1);
    if (t + 1 < nt) { storeA((t & 1) ^ 1); storeW((t & 1) ^ 1); }
  }

  const bool sel2 = (Cout2 != nullptr && col0 >= colSplit);
  const float* bsrc = sel2 ? bias2 : bias;
  TO* outp = sel2 ? Cout2 : Cout;
  const int ldco = sel2 ? ldc2 : ldc;
  const int cbase = sel2 ? (col0 - colSplit) : col0;
  float bv[2];
#pragma unroll
  for (int ni = 0; ni < 2; ++ni) bv[ni] = bsrc[cbase + wc * 32 + ni * 16 + ql];
#pragma unroll
  for (int mi = 0; mi < 2; ++mi) {
#pragma unroll
    for (int r = 0; r < 4; ++r) {
      int row = row0 + wr * 32 + mi * 16 + 4 * g + r;
      if (row >= M) continue;
#pragma unroll
      for (int ni = 0; ni < 2; ++ni) {
        int col = cbase + wc * 32 + ni * 16 + ql;
        float v = acc[mi][ni][r] + bv[ni];
        if (RELU) v = fmaxf(v, 0.f);
        if constexpr (std::is_same<TO, float>::value) {
          outp[(size_t)row * ldco + col] = v;
        } else {
          outp[(size_t)row * ldco + col] = __float2bfloat16(v);
        }
      }
    }
  }
}

// ---------------- standalone 64x64 GEMM kernel ----------------
template <typename TA, typename TO, int RELU>
__global__ __launch_bounds__(256) void mfma_gemm64_kernel(
    const TA* __restrict__ A, const TA* __restrict__ A2,
    const unsigned short* __restrict__ Wt,
    const float* __restrict__ bias, const float* __restrict__ bias2,
    TO* __restrict__ Cout, TO* __restrict__ Cout2,
    int M, int N, int K, int lda, int ldc, int ldc2, int colSplit) {
  __shared__ char smem[32768];
  gemm_body64<TA, TO, RELU>(smem, A, A2, Wt, bias, bias2, Cout, Cout2,
                            M, N, K, lda, ldc, ldc2, colSplit,
                            blockIdx.x, blockIdx.y);
}

// ---------------- fused qkv + value GEMM (BK=64 bodies) ----------------
#define QKV_BLOCKS (6 * 57)   // 342
__global__ __launch_bounds__(256) void qkv_value_kernel(
    const unsigned short* __restrict__ x0bf, const unsigned short* __restrict__ tgtbf,
    const unsigned short* __restrict__ sa_inT, const float* __restrict__ sa_in_b,
    __hip_bfloat16* __restrict__ qkbuf, __hip_bfloat16* __restrict__ vbuf,
    const float* __restrict__ src, const unsigned short* __restrict__ valT,
    const float* __restrict__ val_b, __hip_bfloat16* __restrict__ value) {
  __shared__ char smem[65536];
  int bid = blockIdx.x;
  if (bid < QKV_BLOCKS) {
    gemm_body<unsigned short, __hip_bfloat16, 0>(
        smem, x0bf, tgtbf, sa_inT, sa_in_b, sa_in_b + 512, qkbuf, vbuf,
        ROWS, 768, 256, 256, 512, 256, 512, bid % 6, bid / 6);
  } else {
    int t = bid - QKV_BLOCKS;
    gemm_body<float, __hip_bfloat16, 0>(
        smem, src, nullptr, valT, val_b, nullptr, value, nullptr,
        VROWS, 256, 256, 256, 256, 0, 1 << 30, t & 1, t >> 1);
  }
}

// ---------------- V transpose: vbuf[ROWS][256] -> vT[B][256][VT_LD] ----------------
__global__ __launch_bounds__(256) void vtrans_kernel(
    const unsigned short* __restrict__ vbuf, unsigned short* __restrict__ vT) {
  __shared__ unsigned short tile[32][34];
  int b = blockIdx.y;
  int ct = blockIdx.x & 7;
  int rt = blockIdx.x >> 3;
  int rl = threadIdx.x >> 3, c4 = (threadIdx.x & 7) * 4;
  int gr = min(rt * 32 + rl, NQ_DIM - 1);
  ushort4v v = *reinterpret_cast<const ushort4v*>(
      vbuf + ((size_t)(b * NQ_DIM + gr)) * 256 + ct * 32 + c4);
  tile[rl][c4] = v[0]; tile[rl][c4 + 1] = v[1];
  tile[rl][c4 + 2] = v[2]; tile[rl][c4 + 3] = v[3];
  __syncthreads();
  int cl = threadIdx.x >> 3, r4 = (threadIdx.x & 7) * 4;
  ushort4v o;
  o[0] = tile[r4][cl]; o[1] = tile[r4 + 1][cl];
  o[2] = tile[r4 + 2][cl]; o[3] = tile[r4 + 3][cl];
  *reinterpret_cast<ushort4v*>(
      vT + ((size_t)b * 256 + ct * 32 + cl) * VT_LD + rt * 32 + r4) = o;
}

// ---------------- wave-per-row residual + LayerNorm (no LDS, no barriers) ----------------
__global__ __launch_bounds__(256) void ln_fused_kernel(const float* __restrict__ x,
                                                       const float* __restrict__ y,
                                                       const float* __restrict__ gg,
                                                       const float* __restrict__ bb,
                                                       float* __restrict__ out,
                                                       unsigned short* __restrict__ out2,
                                                       const float* __restrict__ qadd) {
  int row = blockIdx.x * 4 + (threadIdx.x >> 6);
  int lane = threadIdx.x & 63;
  size_t base = (size_t)row * C_DIM + lane * 4;
  float4 xv = *reinterpret_cast<const float4*>(x + base);
  float4 yv = *reinterpret_cast<const float4*>(y + base);
  float v0 = xv.x + yv.x, v1 = xv.y + yv.y, v2 = xv.z + yv.z, v3 = xv.w + yv.w;
  float s = v0 + v1 + v2 + v3;
  float s2 = v0 * v0 + v1 * v1 + v2 * v2 + v3 * v3;
#pragma unroll
  for (int o = 32; o > 0; o >>= 1) {
    s += __shfl_xor(s, o);
    s2 += __shfl_xor(s2, o);
  }
  float mean = s * (1.f / 256.f);
  float var = s2 * (1.f / 256.f) - mean * mean;
  float rstd = rsqrtf(var + 1e-5f);
  float4 gv = *reinterpret_cast<const float4*>(gg + lane * 4);
  float4 bv = *reinterpret_cast<const float4*>(bb + lane * 4);
  float r0 = (v0 - mean) * rstd * gv.x + bv.x;
  float r1 = (v1 - mean) * rstd * gv.y + bv.y;
  float r2 = (v2 - mean) * rstd * gv.z + bv.z;
  float r3 = (v3 - mean) * rstd * gv.w + bv.w;
  float4 ov; ov.x = r0; ov.y = r1; ov.z = r2; ov.w = r3;
  *reinterpret_cast<float4*>(out + base) = ov;
  if (out2) {
    float a0 = r0, a1 = r1, a2 = r2, a3 = r3;
    if (qadd) {
      float4 qv = *reinterpret_cast<const float4*>(qadd + base);
      a0 += qv.x; a1 += qv.y; a2 += qv.z; a3 += qv.w;
    }
    ushort4v u;
    u[0] = f2bf(a0); u[1] = f2bf(a1); u[2] = f2bf(a2); u[3] = f2bf(a3);
    *reinterpret_cast<ushort4v*>(out2 + base) = u;
  }
}

// ---------------- MFMA flash self-attention (barrier-free; V^T direct) ----------------
__global__ __launch_bounds__(256) void self_attn_mfma_kernel(
    const unsigned short* __restrict__ qk, const unsigned short* __restrict__ vT,
    unsigned short* __restrict__ out) {
  __shared__ unsigned short P_lds[4][16][32];
  const int tid = threadIdx.x;
  const int lane = tid & 63, wid = tid >> 6;
  const int g = lane >> 4, ql = lane & 15;
  const int bh = blockIdx.y;
  const int b = bh >> 3, h = bh & 7;
  const int q0 = blockIdx.x * 64 + wid * 16;
  const float scale = 0.17677669529663687f;

  const unsigned short* qk_b = qk + (size_t)b * NQ_DIM * 512;
  const int qrow = min(q0 + ql, NQ_DIM - 1);
  short8v qf = *reinterpret_cast<const short8v*>(
      qk_b + (size_t)qrow * 512 + h * HDIM + 8 * g);
  const unsigned short* kb = qk_b + 256 + h * HDIM + 8 * g;
  const unsigned short* vtb0 = vT + ((size_t)b * 256 + h * HDIM + ql) * VT_LD;
  const unsigned short* vtb1 = vtb0 + 16 * VT_LD;

  float4v o0 = {0.f, 0.f, 0.f, 0.f}, o1 = {0.f, 0.f, 0.f, 0.f};
  float m = -1e30f, lsum = 0.f;

  const int NT = 29;
  for (int kt = 0; kt < NT; ++kt) {
    const int k_base = kt * 32;
    int kr0 = min(k_base + ql, NQ_DIM - 1);
    int kr1 = min(k_base + 16 + ql, NQ_DIM - 1);
    short8v kf0 = *reinterpret_cast<const short8v*>(kb + (size_t)kr0 * 512);
    short8v kf1 = *reinterpret_cast<const short8v*>(kb + (size_t)kr1 * 512);
    float4v z = {0.f, 0.f, 0.f, 0.f};
    float4v s0 = __builtin_amdgcn_mfma_f32_16x16x32_bf16(kf0, qf, z, 0, 0, 0);
    float4v s1 = __builtin_amdgcn_mfma_f32_16x16x32_bf16(kf1, qf, z, 0, 0, 0);

    float s[8];
#pragma unroll
    for (int r = 0; r < 4; ++r) { s[r] = s0[r] * scale; s[4 + r] = s1[r] * scale; }
    if (kt == NT - 1) {
#pragma unroll
      for (int i = 0; i < 8; ++i) {
        int kk = k_base + 16 * (i >> 2) + 4 * g + (i & 3);
        if (kk >= NQ_DIM) s[i] = -1e30f;
      }
    }
    float tm = s[0];
#pragma unroll
    for (int i = 1; i < 8; ++i) tm = fmaxf(tm, s[i]);
    tm = fmaxf(tm, __shfl_xor(tm, 16));
    tm = fmaxf(tm, __shfl_xor(tm, 32));
    float mnew = fmaxf(m, tm);
    float alpha = __expf(m - mnew);
    float p[8];
    float ts = 0.f;
#pragma unroll
    for (int i = 0; i < 8; ++i) { p[i] = __expf(s[i] - mnew); ts += p[i]; }
    ts += __shfl_xor(ts, 16);
    ts += __shfl_xor(ts, 32);
    lsum = lsum * alpha + ts;
    m = mnew;

    ushort4v pp0, pp1;
#pragma unroll
    for (int r = 0; r < 4; ++r) { pp0[r] = f2bf(p[r]); pp1[r] = f2bf(p[4 + r]); }
    *reinterpret_cast<ushort4v*>(&P_lds[wid][ql][4 * g]) = pp0;
    *reinterpret_cast<ushort4v*>(&P_lds[wid][ql][16 + 4 * g]) = pp1;
    asm volatile("s_waitcnt lgkmcnt(0)" ::: "memory");
    __builtin_amdgcn_sched_barrier(0);

    o0 *= alpha;
    o1 *= alpha;

    short8v pf = *reinterpret_cast<const short8v*>(&P_lds[wid][ql][8 * g]);
    short8v vf0 = *reinterpret_cast<const short8v*>(vtb0 + k_base + 8 * g);
    short8v vf1 = *reinterpret_cast<const short8v*>(vtb1 + k_base + 8 * g);
    o0 = __builtin_amdgcn_mfma_f32_16x16x32_bf16(vf0, pf, o0, 0, 0, 0);
    o1 = __builtin_amdgcn_mfma_f32_16x16x32_bf16(vf1, pf, o1, 0, 0, 0);
  }

  float inv = 1.f / lsum;
  if (q0 + ql < NQ_DIM) {
    unsigned short* op = out + ((size_t)(b * NQ_DIM) + q0 + ql) * C_DIM + h * HDIM;
    ushort4v u0, u1;
#pragma unroll
    for (int r = 0; r < 4; ++r) { u0[r] = f2bf(o0[r] * inv); u1[r] = f2bf(o1[r] * inv); }
    *reinterpret_cast<ushort4v*>(op + 4 * g) = u0;
    *reinterpret_cast<ushort4v*>(op + 16 + 4 * g) = u1;
  }
}

// ---------------- MSDA bilinear sampling: 2 lanes x 16 channels, inline softmax ----------------
__global__ __launch_bounds__(256) void msda_sample_kernel(
    const unsigned short* __restrict__ value,
    const float* __restrict__ off,
    const float* __restrict__ awlog,
    const float* __restrict__ refp,
    const int* __restrict__ shapes,
    unsigned short* __restrict__ out) {
  int g = blockIdx.x * 128 + (threadIdx.x >> 1);
  int d16 = threadIdx.x & 1;         // half (16 channels each)
  int h = g & 7;
  int row = g >> 3;
  int b = row / NQ_DIM;

  // inline softmax over the 16 logits of (row, h)
  const float* lg = awlog + (size_t)row * 128 + h * 16;
  float aw16[16];
  float mx = -1e30f;
#pragma unroll
  for (int i = 0; i < 4; ++i) {
    float4 v = *reinterpret_cast<const float4*>(lg + i * 4);
    aw16[i * 4 + 0] = v.x; aw16[i * 4 + 1] = v.y;
    aw16[i * 4 + 2] = v.z; aw16[i * 4 + 3] = v.w;
  }
#pragma unroll
  for (int i = 0; i < 16; ++i) mx = fmaxf(mx, aw16[i]);
  float ssum = 0.f;
#pragma unroll
  for (int i = 0; i < 16; ++i) { aw16[i] = __expf(aw16[i] - mx); ssum += aw16[i]; }
  float sinv = 1.f / ssum;

  float acc[16] = {};
  int start = 0;
  const float* offr = off + (size_t)row * 256 + h * 32;
  const float* rpr  = refp + (size_t)row * NLVL * 2;
  const int chanoff = h * HDIM + d16 * 16;           // 16-channel half
  const unsigned int bbase = (unsigned int)(b * LEN_DIM);
#pragma unroll
  for (int l = 0; l < NLVL; ++l) {
    int Hl = shapes[2 * l], Wl = shapes[2 * l + 1];
    float fx = rpr[2 * l + 0] * (float)Wl - 0.5f;
    float fy = rpr[2 * l + 1] * (float)Hl - 0.5f;
    const unsigned short* vbase = value + (size_t)(bbase + start) * C_DIM + chanoff;
    float4 of0 = *reinterpret_cast<const float4*>(offr + l * 8);
    float4 of1 = *reinterpret_cast<const float4*>(offr + l * 8 + 4);
    float oxs[4] = {of0.x, of0.z, of1.x, of1.z};
    float oys[4] = {of0.y, of0.w, of1.y, of1.w};
#pragma unroll
    for (int p = 0; p < NPT; ++p) {
      float x = fx + oxs[p];
      float y = fy + oys[p];
      float a = aw16[l * 4 + p] * sinv;
      float x0f = floorf(x), y0f = floorf(y);
      float dx = x - x0f, dy = y - y0f;
      int x0 = (int)x0f, y0 = (int)y0f;
      int x1 = x0 + 1, y1 = y0 + 1;
      float wx1 = dx, wx0 = 1.f - dx;
      float wy1 = dy * a, wy0 = (1.f - dy) * a;
      bool vx0 = ((unsigned)x0 < (unsigned)Wl);
      bool vx1 = ((unsigned)x1 < (unsigned)Wl);
      bool vy0 = ((unsigned)y0 < (unsigned)Hl);
      bool vy1 = ((unsigned)y1 < (unsigned)Hl);
      float w00 = (vx0 && vy0) ? wx0 * wy0 : 0.f;
      float w10 = (vx1 && vy0) ? wx1 * wy0 : 0.f;
      float w01 = (vx0 && vy1) ? wx0 * wy1 : 0.f;
      float w11 = (vx1 && vy1) ? wx1 * wy1 : 0.f;
      int x0c = min(max(x0, 0), Wl - 1), x1c = min(max(x1, 0), Wl - 1);
      int y0c = min(max(y0, 0), Hl - 1), y1c = min(max(y1, 0), Hl - 1);
      int r0 = y0c * Wl, r1 = y1c * Wl;
      const unsigned short* p00 = vbase + ((r0 + x0c) << 8);
      const unsigned short* p10 = vbase + ((r0 + x1c) << 8);
      const unsigned short* p01 = vbase + ((r1 + x0c) << 8);
      const unsigned short* p11 = vbase + ((r1 + x1c) << 8);
      ushort8v g00a = *reinterpret_cast<const ushort8v*>(p00);
      ushort8v g00b = *reinterpret_cast<const ushort8v*>(p00 + 8);
      ushort8v g10a = *reinterpret_cast<const ushort8v*>(p10);
      ushort8v g10b = *reinterpret_cast<const ushort8v*>(p10 + 8);
      ushort8v g01a = *reinterpret_cast<const ushort8v*>(p01);
      ushort8v g01b = *reinterpret_cast<const ushort8v*>(p01 + 8);
      ushort8v g11a = *reinterpret_cast<const ushort8v*>(p11);
      ushort8v g11b = *reinterpret_cast<const ushort8v*>(p11 + 8);
#pragma unroll
      for (int j = 0; j < 8; ++j) {
        acc[j]     += w00 * bf2f(g00a[j]) + w10 * bf2f(g10a[j]) +
                      w01 * bf2f(g01a[j]) + w11 * bf2f(g11a[j]);
        acc[8 + j] += w00 * bf2f(g00b[j]) + w10 * bf2f(g10b[j]) +
                      w01 * bf2f(g01b[j]) + w11 * bf2f(g11b[j]);
      }
    }
    start += Hl * Wl;
  }
  ushort8v oA, oB;
#pragma unroll
  for (int j = 0; j < 8; ++j) { oA[j] = f2bf(acc[j]); oB[j] = f2bf(acc[8 + j]); }
  unsigned short* op = out + (size_t)row * C_DIM + chanoff;
  *reinterpret_cast<ushort8v*>(op) = oA;
  *reinterpret_cast<ushort8v*>(op + 8) = oB;
}

// =====================================================================
extern "C" void kernel_launch(void* const* d_in, const int* in_sizes, int n_in,
                              void* d_out, int out_size, void* d_ws, size_t ws_size,
                              hipStream_t stream) {
  const float* tgt      = (const float*)d_in[0];
  const float* qpos     = (const float*)d_in[1];
  const float* refp     = (const float*)d_in[2];
  const float* src      = (const float*)d_in[3];
  const int*   shapes   = (const int*)d_in[4];
  const float* sa_in_w  = (const float*)d_in[5];
  const float* sa_in_b  = (const float*)d_in[6];
  const float* sa_out_w = (const float*)d_in[7];
  const float* sa_out_b = (const float*)d_in[8];
  const float* ln2_g    = (const float*)d_in[9];
  const float* ln2_b    = (const float*)d_in[10];
  const float* off_w    = (const float*)d_in[11];
  const float* off_b    = (const float*)d_in[12];
  const float* attw_w   = (const float*)d_in[13];
  const float* attw_b   = (const float*)d_in[14];
  const float* val_w    = (const float*)d_in[15];
  const float* val_b    = (const float*)d_in[16];
  const float* proj_w   = (const float*)d_in[17];
  const float* proj_b   = (const float*)d_in[18];
  const float* ln1_g    = (const float*)d_in[19];
  const float* ln1_b    = (const float*)d_in[20];
  const float* lin1_w   = (const float*)d_in[21];
  const float* lin1_b   = (const float*)d_in[22];
  const float* lin2_w   = (const float*)d_in[23];
  const float* lin2_b   = (const float*)d_in[24];
  const float* ln3_g    = (const float*)d_in[25];
  const float* ln3_b    = (const float*)d_in[26];

  char* ws = (char*)d_ws;
  size_t off_b_ws = 0;
  auto alloc = [&](size_t bytes) {
    char* p = ws + off_b_ws;
    off_b_ws += (bytes + 255) & ~(size_t)255;
    return p;
  };
  unsigned short* wT     = (unsigned short*)alloc((size_t)1015808 * 2);
  unsigned short* value  = (unsigned short*)alloc((size_t)VROWS * C_DIM * 2);
  unsigned short* qkbuf  = (unsigned short*)alloc((size_t)ROWS * 512 * 2);
  unsigned short* vbuf   = (unsigned short*)alloc((size_t)ROWS * 256 * 2);
  unsigned short* vTbuf  = (unsigned short*)alloc((size_t)BB * 256 * VT_LD * 2);
  unsigned short* tgtbf  = (unsigned short*)alloc((size_t)ROWS * C_DIM * 2);
  unsigned short* X0bf   = (unsigned short*)alloc((size_t)ROWS * C_DIM * 2);
  unsigned short* attnbf = (unsigned short*)alloc((size_t)ROWS * C_DIM * 2);
  unsigned short* X3bf   = (unsigned short*)alloc((size_t)ROWS * C_DIM * 2);
  unsigned short* sampbf = (unsigned short*)alloc((size_t)ROWS * C_DIM * 2);
  unsigned short* X6bf   = (unsigned short*)alloc((size_t)ROWS * C_DIM * 2);
  unsigned short* hidbf  = (unsigned short*)alloc((size_t)ROWS * DFF_DIM * 2);
  float* X1 = (float*)alloc((size_t)ROWS * C_DIM * 4);
  float* X2 = (float*)alloc((size_t)ROWS * C_DIM * 4);
  float* X4 = (float*)alloc((size_t)ROWS * C_DIM * 4);
  float* X5 = (float*)alloc((size_t)ROWS * 128 * 4);
  float* X6 = (float*)alloc((size_t)ROWS * C_DIM * 4);
  if (off_b_ws > ws_size) return;

  // wT segment offsets (order must match wprep_kernel)
  unsigned short* sa_inT = wT + 0;        // [768][256]
  unsigned short* sa_outT = wT + 196608;  // [256][256]
  unsigned short* offT   = wT + 262144;   // [256][256] (attwT contiguous after)
  unsigned short* valT   = wT + 360448;
  unsigned short* projT  = wT + 425984;
  unsigned short* lin1T  = wT + 491520;   // [1024][256]
  unsigned short* lin2T  = wT + 753664;   // [256][1024]

  dim3 blk(256);
  const int MBV = (VROWS + 127) / 128;        // 831
  const int MB64 = (ROWS + 63) / 64;          // 113
  int n4 = ROWS * C_DIM / 4;
  int prepBlocks = (n4 + 255) / 256;
  const int lnBlocks = ROWS / 4;              // 1800

  // ---- merged weight-transpose + bf16 prep ----
  wprep_kernel<<<WCONV_BLOCKS + prepBlocks, blk, 0, stream>>>(
      sa_in_w, sa_out_w, off_w, attw_w, val_w, proj_w, lin1_w, lin2_w, wT,
      tgt, qpos, tgtbf, X0bf, n4);

  // ---- fused qkv GEMM + value GEMM (BK=64) ----
  qkv_value_kernel<<<QKV_BLOCKS + 2 * MBV, blk, 0, stream>>>(
      X0bf, tgtbf, sa_inT, sa_in_b, (__hip_bfloat16*)qkbuf, (__hip_bfloat16*)vbuf,
      src, valT, val_b, (__hip_bfloat16*)value);

  // ---- V transpose ----
  vtrans_kernel<<<dim3(8 * 29, BB), blk, 0, stream>>>(vbuf, vTbuf);

  // ---- self-attention ----
  self_attn_mfma_kernel<<<dim3(15, 64), blk, 0, stream>>>(qkbuf, vTbuf, attnbf);

  // ---- self-attn out proj + LN2 ----
  mfma_gemm64_kernel<unsigned short, float, 0><<<dim3(4, MB64), blk, 0, stream>>>(
      attnbf, nullptr, sa_outT, sa_out_b, nullptr,
      X1, nullptr, ROWS, 256, 256, 256, 256, 0, 1 << 30);
  ln_fused_kernel<<<lnBlocks, blk, 0, stream>>>(tgt, X1, ln2_g, ln2_b, X2, X3bf, qpos);

  // ---- MSDeformAttn ----
  mfma_gemm64_kernel<unsigned short, float, 0><<<dim3(6, MB64), blk, 0, stream>>>(
      X3bf, nullptr, offT, off_b, attw_b,
      X4, X5, ROWS, 384, 256, 256, 256, 128, 256);
  msda_sample_kernel<<<ROWS * NHEAD / 128, blk, 0, stream>>>(
      value, X4, X5, refp, shapes, sampbf);
  mfma_gemm64_kernel<unsigned short, float, 0><<<dim3(4, MB64), blk, 0, stream>>>(
      sampbf, nullptr, projT, proj_b, nullptr,
      X1, nullptr, ROWS, 256, 256, 256, 256, 0, 1 << 30);
  ln_fused_kernel<<<lnBlocks, blk, 0, stream>>>(X2, X1, ln1_g, ln1_b, X6, X6bf, nullptr);

  // ---- FFN ----
  mfma_gemm64_kernel<unsigned short, __hip_bfloat16, 1><<<dim3(16, MB64), blk, 0, stream>>>(
      X6bf, nullptr, lin1T, lin1_b, nullptr,
      (__hip_bfloat16*)hidbf, nullptr, ROWS, 1024, 256, 256, 1024, 0, 1 << 30);
  mfma_gemm64_kernel<unsigned short, float, 0><<<dim3(4, MB64), blk, 0, stream>>>(
      hidbf, nullptr, lin2T, lin2_b, nullptr,
      X1, nullptr, ROWS, 256, 1024, 1024, 256, 0, 1 << 30);
  ln_fused_kernel<<<lnBlocks, blk, 0, stream>>>(X6, X1, ln3_g, ln3_b, (float*)d_out, nullptr, nullptr);
}

// Round 19
// 199.466 us; speedup vs baseline: 1.1136x; 1.1136x over previous
//
#include <hip/hip_runtime.h>
#include <hip/hip_bf16.h>
#include <type_traits>

#define C_DIM 256
#define NHEAD 8
#define HDIM 32
#define NLVL 4
#define NPT 4
#define DFF_DIM 1024
#define BB 8
#define NQ_DIM 900
#define LEN_DIM 13294
#define ROWS (BB * NQ_DIM)      // 7200
#define VROWS (BB * LEN_DIM)    // 106352
#define VT_LD 928               // padded stride for vT rows (29*32)

typedef __attribute__((ext_vector_type(8))) short short8v;
typedef __attribute__((ext_vector_type(8))) unsigned short ushort8v;
typedef __attribute__((ext_vector_type(4))) float float4v;
typedef __attribute__((ext_vector_type(4))) unsigned short ushort4v;

__device__ __forceinline__ float bf2f(unsigned short u) {
  union { unsigned int i; float f; } v; v.i = ((unsigned int)u) << 16; return v.f;
}
__device__ __forceinline__ unsigned short f2bf(float f) {
  __hip_bfloat16 h = __float2bfloat16(f);
  return *reinterpret_cast<unsigned short*>(&h);
}

// ---------------- merged: weight transpose+convert AND tgt/x0 bf16 prep ----------------
#define WCONV_BLOCKS 2048
__global__ __launch_bounds__(256) void wprep_kernel(
    const float* __restrict__ w0, const float* __restrict__ w1,
    const float* __restrict__ w2, const float* __restrict__ w3,
    const float* __restrict__ w4, const float* __restrict__ w5,
    const float* __restrict__ w6, const float* __restrict__ w7,
    unsigned short* __restrict__ out,
    const float* __restrict__ tgt, const float* __restrict__ qpos,
    unsigned short* __restrict__ tgtbf, unsigned short* __restrict__ x0bf, int n4) {
  int bid = blockIdx.x;
  if (bid < WCONV_BLOCKS) {
    const int Ks[8] = {256, 256, 256, 256, 256, 256, 256, 1024};
    const int Ns[8] = {768, 256, 256, 128, 256, 256, 1024, 256};
    const int Oo[8] = {0, 196608, 262144, 327680, 360448, 425984, 491520, 753664};
    int w = bid >> 8, bx = bid & 255;
    int K = Ks[w], N = Ns[w];
    int ntx = N >> 5, nty = K >> 5;
    if (bx >= ntx * nty) return;
    int tx = bx % ntx, ty = bx / ntx;
    const float* W = w == 0 ? w0 : w == 1 ? w1 : w == 2 ? w2 : w == 3 ? w3
                   : w == 4 ? w4 : w == 5 ? w5 : w == 6 ? w6 : w7;
    __shared__ float tile[32][33];
    int c = threadIdx.x & 31, rg = threadIdx.x >> 5;
#pragma unroll
    for (int j = 0; j < 4; ++j) {
      int k = ty * 32 + rg * 4 + j;
      tile[rg * 4 + j][c] = W[(size_t)k * N + tx * 32 + c];
    }
    __syncthreads();
    unsigned short* o = out + Oo[w];
#pragma unroll
    for (int j = 0; j < 4; ++j) {
      int n = tx * 32 + rg * 4 + j;
      o[(size_t)n * K + ty * 32 + c] = f2bf(tile[c][rg * 4 + j]);
    }
  } else {
    int i = (bid - WCONV_BLOCKS) * 256 + threadIdx.x;
    if (i < n4) {
      float4 x = reinterpret_cast<const float4*>(tgt)[i];
      float4 y = reinterpret_cast<const float4*>(qpos)[i];
      ushort4v u1, u2;
      u1[0] = f2bf(x.x); u1[1] = f2bf(x.y); u1[2] = f2bf(x.z); u1[3] = f2bf(x.w);
      u2[0] = f2bf(x.x + y.x); u2[1] = f2bf(x.y + y.y);
      u2[2] = f2bf(x.z + y.z); u2[3] = f2bf(x.w + y.w);
      *reinterpret_cast<ushort4v*>(tgtbf + (size_t)i * 4) = u1;
      *reinterpret_cast<ushort4v*>(x0bf + (size_t)i * 4) = u2;
    }
  }
}

// ---------------- GEMM body 128x128, BK=64, XOR-swizzled LDS ----------------
template <typename TA, typename TO, int RELU>
__device__ __forceinline__ void gemm_body(
    char* smem,  // 65536 bytes
    const TA* __restrict__ A, const TA* __restrict__ A2,
    const unsigned short* __restrict__ Wt,
    const float* __restrict__ bias, const float* __restrict__ bias2,
    TO* __restrict__ Cout, TO* __restrict__ Cout2,
    int M, int N, int K, int lda, int ldc, int ldc2, int colSplit,
    int bx, int by) {
  const int tid = threadIdx.x;
  const int lane = tid & 63, wid = tid >> 6;
  const int g = lane >> 4, ql = lane & 15;
  const int wr = wid >> 1, wc = wid & 1;
  const int row0 = by * 128, col0 = bx * 128;

  const TA* Ause = (A2 != nullptr && col0 >= colSplit) ? A2 : A;

  float4v acc[4][4];
#pragma unroll
  for (int i = 0; i < 4; ++i)
#pragma unroll
    for (int j = 0; j < 4; ++j) acc[i][j] = (float4v){0.f, 0.f, 0.f, 0.f};

  float4 areg_f[8];
  ushort8v areg_b[4];
  ushort8v wreg[4];

  auto loadA = [&](int k0) {
    if constexpr (std::is_same<TA, float>::value) {
#pragma unroll
      for (int j = 0; j < 8; ++j) {
        int c = tid + 256 * j;
        int row = c >> 4, ch = c & 15;
        int gr = min(row0 + row, M - 1);
        areg_f[j] = *reinterpret_cast<const float4*>(Ause + (size_t)gr * lda + k0 + ch * 4);
      }
    } else {
#pragma unroll
      for (int j = 0; j < 4; ++j) {
        int c = tid + 256 * j;
        int row = c >> 3, ch = c & 7;
        int gr = min(row0 + row, M - 1);
        areg_b[j] = *reinterpret_cast<const ushort8v*>(
            reinterpret_cast<const unsigned short*>(Ause) + (size_t)gr * lda + k0 + ch * 8);
      }
    }
  };
  auto loadW = [&](int k0) {
#pragma unroll
    for (int j = 0; j < 4; ++j) {
      int c = tid + 256 * j;
      int row = c >> 3, ch = c & 7;
      wreg[j] = *reinterpret_cast<const ushort8v*>(
          Wt + (size_t)(col0 + row) * K + k0 + ch * 8);
    }
  };
  auto storeA = [&](int buf) {
    char* base = smem + buf * 16384;
    if constexpr (std::is_same<TA, float>::value) {
#pragma unroll
      for (int j = 0; j < 8; ++j) {
        int c = tid + 256 * j;
        int row = c >> 4, ch = c & 15;
        ushort4v u;
        u[0] = f2bf(areg_f[j].x); u[1] = f2bf(areg_f[j].y);
        u[2] = f2bf(areg_f[j].z); u[3] = f2bf(areg_f[j].w);
        int off = row * 128 + ((ch * 8) ^ ((row & 7) << 4));
        *reinterpret_cast<ushort4v*>(base + off) = u;
      }
    } else {
#pragma unroll
      for (int j = 0; j < 4; ++j) {
        int c = tid + 256 * j;
        int row = c >> 3, ch = c & 7;
        int off = row * 128 + ((ch * 16) ^ ((row & 7) << 4));
        *reinterpret_cast<ushort8v*>(base + off) = areg_b[j];
      }
    }
  };
  auto storeW = [&](int buf) {
    char* base = smem + 32768 + buf * 16384;
#pragma unroll
    for (int j = 0; j < 4; ++j) {
      int c = tid + 256 * j;
      int row = c >> 3, ch = c & 7;
      int off = row * 128 + ((ch * 16) ^ ((row & 7) << 4));
      *reinterpret_cast<ushort8v*>(base + off) = wreg[j];
    }
  };
  auto compute = [&](int buf) {
    const char* abase = smem + buf * 16384;
    const char* wbase = smem + 32768 + buf * 16384;
#pragma unroll
    for (int kk = 0; kk < 2; ++kk) {
      short8v af[4], bfr[4];
#pragma unroll
      for (int mi = 0; mi < 4; ++mi) {
        int r = wr * 64 + mi * 16 + ql;
        int off = r * 128 + ((kk * 64 + g * 16) ^ ((r & 7) << 4));
        af[mi] = *reinterpret_cast<const short8v*>(abase + off);
      }
#pragma unroll
      for (int ni = 0; ni < 4; ++ni) {
        int r = wc * 64 + ni * 16 + ql;
        int off = r * 128 + ((kk * 64 + g * 16) ^ ((r & 7) << 4));
        bfr[ni] = *reinterpret_cast<const short8v*>(wbase + off);
      }
#pragma unroll
      for (int mi = 0; mi < 4; ++mi)
#pragma unroll
        for (int ni = 0; ni < 4; ++ni)
          acc[mi][ni] = __builtin_amdgcn_mfma_f32_16x16x32_bf16(af[mi], bfr[ni], acc[mi][ni], 0, 0, 0);
    }
  };

  const int nt = K >> 6;   // BK = 64
  loadA(0); loadW(0);
  storeA(0); storeW(0);

  for (int t = 0; t < nt; ++t) {
    __syncthreads();
    if (t + 1 < nt) { loadA((t + 1) << 6); loadW((t + 1) << 6); }
    compute(t & 1);
    if (t + 1 < nt) { storeA((t & 1) ^ 1); storeW((t & 1) ^ 1); }
  }

  const bool sel2 = (Cout2 != nullptr && col0 >= colSplit);
  const float* bsrc = sel2 ? bias2 : bias;
  TO* outp = sel2 ? Cout2 : Cout;
  const int ldco = sel2 ? ldc2 : ldc;
  const int cbase = sel2 ? (col0 - colSplit) : col0;
  float bv[4];
#pragma unroll
  for (int ni = 0; ni < 4; ++ni) bv[ni] = bsrc[cbase + wc * 64 + ni * 16 + ql];
#pragma unroll
  for (int mi = 0; mi < 4; ++mi) {
#pragma unroll
    for (int r = 0; r < 4; ++r) {
      int row = row0 + wr * 64 + mi * 16 + 4 * g + r;
      if (row >= M) continue;
#pragma unroll
      for (int ni = 0; ni < 4; ++ni) {
        int col = cbase + wc * 64 + ni * 16 + ql;
        float v = acc[mi][ni][r] + bv[ni];
        if (RELU) v = fmaxf(v, 0.f);
        if constexpr (std::is_same<TO, float>::value) {
          outp[(size_t)row * ldco + col] = v;
        } else {
          outp[(size_t)row * ldco + col] = __float2bfloat16(v);
        }
      }
    }
  }
}

// ---------------- GEMM body 64x64, BK=64, XOR-swizzled LDS ----------------
template <typename TA, typename TO, int RELU>
__device__ __forceinline__ void gemm_body64(
    char* smem,  // 32768 bytes
    const TA* __restrict__ A, const TA* __restrict__ A2,
    const unsigned short* __restrict__ Wt,
    const float* __restrict__ bias, const float* __restrict__ bias2,
    TO* __restrict__ Cout, TO* __restrict__ Cout2,
    int M, int N, int K, int lda, int ldc, int ldc2, int colSplit,
    int bx, int by) {
  const int tid = threadIdx.x;
  const int lane = tid & 63, wid = tid >> 6;
  const int g = lane >> 4, ql = lane & 15;
  const int wr = wid >> 1, wc = wid & 1;
  const int row0 = by * 64, col0 = bx * 64;

  const TA* Ause = (A2 != nullptr && col0 >= colSplit) ? A2 : A;

  float4v acc[2][2];
#pragma unroll
  for (int i = 0; i < 2; ++i)
#pragma unroll
    for (int j = 0; j < 2; ++j) acc[i][j] = (float4v){0.f, 0.f, 0.f, 0.f};

  float4 areg_f[4];
  ushort8v areg_b[2];
  ushort8v wreg[2];

  auto loadA = [&](int k0) {
    if constexpr (std::is_same<TA, float>::value) {
#pragma unroll
      for (int j = 0; j < 4; ++j) {
        int c = tid + 256 * j;
        int row = c >> 4, ch = c & 15;
        int gr = min(row0 + row, M - 1);
        areg_f[j] = *reinterpret_cast<const float4*>(Ause + (size_t)gr * lda + k0 + ch * 4);
      }
    } else {
#pragma unroll
      for (int j = 0; j < 2; ++j) {
        int c = tid + 256 * j;
        int row = c >> 3, ch = c & 7;
        int gr = min(row0 + row, M - 1);
        areg_b[j] = *reinterpret_cast<const ushort8v*>(
            reinterpret_cast<const unsigned short*>(Ause) + (size_t)gr * lda + k0 + ch * 8);
      }
    }
  };
  auto loadW = [&](int k0) {
#pragma unroll
    for (int j = 0; j < 2; ++j) {
      int c = tid + 256 * j;
      int row = c >> 3, ch = c & 7;
      wreg[j] = *reinterpret_cast<const ushort8v*>(
          Wt + (size_t)(col0 + row) * K + k0 + ch * 8);
    }
  };
  auto storeA = [&](int buf) {
    char* base = smem + buf * 8192;
    if constexpr (std::is_same<TA, float>::value) {
#pragma unroll
      for (int j = 0; j < 4; ++j) {
        int c = tid + 256 * j;
        int row = c >> 4, ch = c & 15;
        ushort4v u;
        u[0] = f2bf(areg_f[j].x); u[1] = f2bf(areg_f[j].y);
        u[2] = f2bf(areg_f[j].z); u[3] = f2bf(areg_f[j].w);
        int off = row * 128 + ((ch * 8) ^ ((row & 7) << 4));
        *reinterpret_cast<ushort4v*>(base + off) = u;
      }
    } else {
#pragma unroll
      for (int j = 0; j < 2; ++j) {
        int c = tid + 256 * j;
        int row = c >> 3, ch = c & 7;
        int off = row * 128 + ((ch * 16) ^ ((row & 7) << 4));
        *reinterpret_cast<ushort8v*>(base + off) = areg_b[j];
      }
    }
  };
  auto storeW = [&](int buf) {
    char* base = smem + 16384 + buf * 8192;
#pragma unroll
    for (int j = 0; j < 2; ++j) {
      int c = tid + 256 * j;
      int row = c >> 3, ch = c & 7;
      int off = row * 128 + ((ch * 16) ^ ((row & 7) << 4));
      *reinterpret_cast<ushort8v*>(base + off) = wreg[j];
    }
  };
  auto compute = [&](int buf) {
    const char* abase = smem + buf * 8192;
    const char* wbase = smem + 16384 + buf * 8192;
#pragma unroll
    for (int kk = 0; kk < 2; ++kk) {
      short8v af[2], bfr[2];
#pragma unroll
      for (int mi = 0; mi < 2; ++mi) {
        int r = wr * 32 + mi * 16 + ql;
        int off = r * 128 + ((kk * 64 + g * 16) ^ ((r & 7) << 4));
        af[mi] = *reinterpret_cast<const short8v*>(abase + off);
      }
#pragma unroll
      for (int ni = 0; ni < 2; ++ni) {
        int r = wc * 32 + ni * 16 + ql;
        int off = r * 128 + ((kk * 64 + g * 16) ^ ((r & 7) << 4));
        bfr[ni] = *reinterpret_cast<const short8v*>(wbase + off);
      }
#pragma unroll
      for (int mi = 0; mi < 2; ++mi)
#pragma unroll
        for (int ni = 0; ni < 2; ++ni)
          acc[mi][ni] = __builtin_amdgcn_mfma_f32_16x16x32_bf16(af[mi], bfr[ni], acc[mi][ni], 0, 0, 0);
    }
  };

  const int nt = K >> 6;
  loadA(0); loadW(0);
  storeA(0); storeW(0);

  for (int t = 0; t < nt; ++t) {
    __syncthreads();
    if (t + 1 < nt) { loadA((t + 1) << 6); loadW((t + 1) << 6); }
    compute(t & 1);
    if (t + 1 < nt) { storeA((t & 1) ^ 1); storeW((t & 1) ^ 1); }
  }

  const bool sel2 = (Cout2 != nullptr && col0 >= colSplit);
  const float* bsrc = sel2 ? bias2 : bias;
  TO* outp = sel2 ? Cout2 : Cout;
  const int ldco = sel2 ? ldc2 : ldc;
  const int cbase = sel2 ? (col0 - colSplit) : col0;
  float bv[2];
#pragma unroll
  for (int ni = 0; ni < 2; ++ni) bv[ni] = bsrc[cbase + wc * 32 + ni * 16 + ql];
#pragma unroll
  for (int mi = 0; mi < 2; ++mi) {
#pragma unroll
    for (int r = 0; r < 4; ++r) {
      int row = row0 + wr * 32 + mi * 16 + 4 * g + r;
      if (row >= M) continue;
#pragma unroll
      for (int ni = 0; ni < 2; ++ni) {
        int col = cbase + wc * 32 + ni * 16 + ql;
        float v = acc[mi][ni][r] + bv[ni];
        if (RELU) v = fmaxf(v, 0.f);
        if constexpr (std::is_same<TO, float>::value) {
          outp[(size_t)row * ldco + col] = v;
        } else {
          outp[(size_t)row * ldco + col] = __float2bfloat16(v);
        }
      }
    }
  }
}

// ---------------- standalone 64x64 GEMM kernel ----------------
template <typename TA, typename TO, int RELU>
__global__ __launch_bounds__(256) void mfma_gemm64_kernel(
    const TA* __restrict__ A, const TA* __restrict__ A2,
    const unsigned short* __restrict__ Wt,
    const float* __restrict__ bias, const float* __restrict__ bias2,
    TO* __restrict__ Cout, TO* __restrict__ Cout2,
    int M, int N, int K, int lda, int ldc, int ldc2, int colSplit) {
  __shared__ char smem[32768];
  gemm_body64<TA, TO, RELU>(smem, A, A2, Wt, bias, bias2, Cout, Cout2,
                            M, N, K, lda, ldc, ldc2, colSplit,
                            blockIdx.x, blockIdx.y);
}

// ---------------- fused qkv + value GEMM (BK=64 bodies) ----------------
#define QKV_BLOCKS (6 * 57)   // 342
__global__ __launch_bounds__(256) void qkv_value_kernel(
    const unsigned short* __restrict__ x0bf, const unsigned short* __restrict__ tgtbf,
    const unsigned short* __restrict__ sa_inT, const float* __restrict__ sa_in_b,
    __hip_bfloat16* __restrict__ qkbuf, __hip_bfloat16* __restrict__ vbuf,
    const float* __restrict__ src, const unsigned short* __restrict__ valT,
    const float* __restrict__ val_b, __hip_bfloat16* __restrict__ value) {
  __shared__ char smem[65536];
  int bid = blockIdx.x;
  if (bid < QKV_BLOCKS) {
    gemm_body<unsigned short, __hip_bfloat16, 0>(
        smem, x0bf, tgtbf, sa_inT, sa_in_b, sa_in_b + 512, qkbuf, vbuf,
        ROWS, 768, 256, 256, 512, 256, 512, bid % 6, bid / 6);
  } else {
    int t = bid - QKV_BLOCKS;
    gemm_body<float, __hip_bfloat16, 0>(
        smem, src, nullptr, valT, val_b, nullptr, value, nullptr,
        VROWS, 256, 256, 256, 256, 0, 1 << 30, t & 1, t >> 1);
  }
}

// ---------------- V transpose: vbuf[ROWS][256] -> vT[B][256][VT_LD] ----------------
__global__ __launch_bounds__(256) void vtrans_kernel(
    const unsigned short* __restrict__ vbuf, unsigned short* __restrict__ vT) {
  __shared__ unsigned short tile[32][34];
  int b = blockIdx.y;
  int ct = blockIdx.x & 7;
  int rt = blockIdx.x >> 3;
  int rl = threadIdx.x >> 3, c4 = (threadIdx.x & 7) * 4;
  int gr = min(rt * 32 + rl, NQ_DIM - 1);
  ushort4v v = *reinterpret_cast<const ushort4v*>(
      vbuf + ((size_t)(b * NQ_DIM + gr)) * 256 + ct * 32 + c4);
  tile[rl][c4] = v[0]; tile[rl][c4 + 1] = v[1];
  tile[rl][c4 + 2] = v[2]; tile[rl][c4 + 3] = v[3];
  __syncthreads();
  int cl = threadIdx.x >> 3, r4 = (threadIdx.x & 7) * 4;
  ushort4v o;
  o[0] = tile[r4][cl]; o[1] = tile[r4 + 1][cl];
  o[2] = tile[r4 + 2][cl]; o[3] = tile[r4 + 3][cl];
  *reinterpret_cast<ushort4v*>(
      vT + ((size_t)b * 256 + ct * 32 + cl) * VT_LD + rt * 32 + r4) = o;
}

// ---------------- wave-per-row residual + LayerNorm (no LDS, no barriers) ----------------
__global__ __launch_bounds__(256) void ln_fused_kernel(const float* __restrict__ x,
                                                       const float* __restrict__ y,
                                                       const float* __restrict__ gg,
                                                       const float* __restrict__ bb,
                                                       float* __restrict__ out,
                                                       unsigned short* __restrict__ out2,
                                                       const float* __restrict__ qadd) {
  int row = blockIdx.x * 4 + (threadIdx.x >> 6);
  int lane = threadIdx.x & 63;
  size_t base = (size_t)row * C_DIM + lane * 4;
  float4 xv = *reinterpret_cast<const float4*>(x + base);
  float4 yv = *reinterpret_cast<const float4*>(y + base);
  float v0 = xv.x + yv.x, v1 = xv.y + yv.y, v2 = xv.z + yv.z, v3 = xv.w + yv.w;
  float s = v0 + v1 + v2 + v3;
  float s2 = v0 * v0 + v1 * v1 + v2 * v2 + v3 * v3;
#pragma unroll
  for (int o = 32; o > 0; o >>= 1) {
    s += __shfl_xor(s, o);
    s2 += __shfl_xor(s2, o);
  }
  float mean = s * (1.f / 256.f);
  float var = s2 * (1.f / 256.f) - mean * mean;
  float rstd = rsqrtf(var + 1e-5f);
  float4 gv = *reinterpret_cast<const float4*>(gg + lane * 4);
  float4 bv = *reinterpret_cast<const float4*>(bb + lane * 4);
  float r0 = (v0 - mean) * rstd * gv.x + bv.x;
  float r1 = (v1 - mean) * rstd * gv.y + bv.y;
  float r2 = (v2 - mean) * rstd * gv.z + bv.z;
  float r3 = (v3 - mean) * rstd * gv.w + bv.w;
  float4 ov; ov.x = r0; ov.y = r1; ov.z = r2; ov.w = r3;
  *reinterpret_cast<float4*>(out + base) = ov;
  if (out2) {
    float a0 = r0, a1 = r1, a2 = r2, a3 = r3;
    if (qadd) {
      float4 qv = *reinterpret_cast<const float4*>(qadd + base);
      a0 += qv.x; a1 += qv.y; a2 += qv.z; a3 += qv.w;
    }
    ushort4v u;
    u[0] = f2bf(a0); u[1] = f2bf(a1); u[2] = f2bf(a2); u[3] = f2bf(a3);
    *reinterpret_cast<ushort4v*>(out2 + base) = u;
  }
}

// ---------------- MFMA flash self-attention (barrier-free; V^T direct) ----------------
__global__ __launch_bounds__(256) void self_attn_mfma_kernel(
    const unsigned short* __restrict__ qk, const unsigned short* __restrict__ vT,
    unsigned short* __restrict__ out) {
  __shared__ unsigned short P_lds[4][16][32];
  const int tid = threadIdx.x;
  const int lane = tid & 63, wid = tid >> 6;
  const int g = lane >> 4, ql = lane & 15;
  const int bh = blockIdx.y;
  const int b = bh >> 3, h = bh & 7;
  const int q0 = blockIdx.x * 64 + wid * 16;
  const float scale = 0.17677669529663687f;

  const unsigned short* qk_b = qk + (size_t)b * NQ_DIM * 512;
  const int qrow = min(q0 + ql, NQ_DIM - 1);
  short8v qf = *reinterpret_cast<const short8v*>(
      qk_b + (size_t)qrow * 512 + h * HDIM + 8 * g);
  const unsigned short* kb = qk_b + 256 + h * HDIM + 8 * g;
  const unsigned short* vtb0 = vT + ((size_t)b * 256 + h * HDIM + ql) * VT_LD;
  const unsigned short* vtb1 = vtb0 + 16 * VT_LD;

  float4v o0 = {0.f, 0.f, 0.f, 0.f}, o1 = {0.f, 0.f, 0.f, 0.f};
  float m = -1e30f, lsum = 0.f;

  const int NT = 29;
  for (int kt = 0; kt < NT; ++kt) {
    const int k_base = kt * 32;
    int kr0 = min(k_base + ql, NQ_DIM - 1);
    int kr1 = min(k_base + 16 + ql, NQ_DIM - 1);
    short8v kf0 = *reinterpret_cast<const short8v*>(kb + (size_t)kr0 * 512);
    short8v kf1 = *reinterpret_cast<const short8v*>(kb + (size_t)kr1 * 512);
    float4v z = {0.f, 0.f, 0.f, 0.f};
    float4v s0 = __builtin_amdgcn_mfma_f32_16x16x32_bf16(kf0, qf, z, 0, 0, 0);
    float4v s1 = __builtin_amdgcn_mfma_f32_16x16x32_bf16(kf1, qf, z, 0, 0, 0);

    float s[8];
#pragma unroll
    for (int r = 0; r < 4; ++r) { s[r] = s0[r] * scale; s[4 + r] = s1[r] * scale; }
    if (kt == NT - 1) {
#pragma unroll
      for (int i = 0; i < 8; ++i) {
        int kk = k_base + 16 * (i >> 2) + 4 * g + (i & 3);
        if (kk >= NQ_DIM) s[i] = -1e30f;
      }
    }
    float tm = s[0];
#pragma unroll
    for (int i = 1; i < 8; ++i) tm = fmaxf(tm, s[i]);
    tm = fmaxf(tm, __shfl_xor(tm, 16));
    tm = fmaxf(tm, __shfl_xor(tm, 32));
    float mnew = fmaxf(m, tm);
    float alpha = __expf(m - mnew);
    float p[8];
    float ts = 0.f;
#pragma unroll
    for (int i = 0; i < 8; ++i) { p[i] = __expf(s[i] - mnew); ts += p[i]; }
    ts += __shfl_xor(ts, 16);
    ts += __shfl_xor(ts, 32);
    lsum = lsum * alpha + ts;
    m = mnew;

    ushort4v pp0, pp1;
#pragma unroll
    for (int r = 0; r < 4; ++r) { pp0[r] = f2bf(p[r]); pp1[r] = f2bf(p[4 + r]); }
    *reinterpret_cast<ushort4v*>(&P_lds[wid][ql][4 * g]) = pp0;
    *reinterpret_cast<ushort4v*>(&P_lds[wid][ql][16 + 4 * g]) = pp1;
    asm volatile("s_waitcnt lgkmcnt(0)" ::: "memory");
    __builtin_amdgcn_sched_barrier(0);

    o0 *= alpha;
    o1 *= alpha;

    short8v pf = *reinterpret_cast<const short8v*>(&P_lds[wid][ql][8 * g]);
    short8v vf0 = *reinterpret_cast<const short8v*>(vtb0 + k_base + 8 * g);
    short8v vf1 = *reinterpret_cast<const short8v*>(vtb1 + k_base + 8 * g);
    o0 = __builtin_amdgcn_mfma_f32_16x16x32_bf16(vf0, pf, o0, 0, 0, 0);
    o1 = __builtin_amdgcn_mfma_f32_16x16x32_bf16(vf1, pf, o1, 0, 0, 0);
  }

  float inv = 1.f / lsum;
  if (q0 + ql < NQ_DIM) {
    unsigned short* op = out + ((size_t)(b * NQ_DIM) + q0 + ql) * C_DIM + h * HDIM;
    ushort4v u0, u1;
#pragma unroll
    for (int r = 0; r < 4; ++r) { u0[r] = f2bf(o0[r] * inv); u1[r] = f2bf(o1[r] * inv); }
    *reinterpret_cast<ushort4v*>(op + 4 * g) = u0;
    *reinterpret_cast<ushort4v*>(op + 16 + 4 * g) = u1;
  }
}

// ---------------- MSDA bilinear sampling: 4 lanes x 8 channels, inline softmax ----------------
__global__ __launch_bounds__(256) void msda_sample_kernel(
    const unsigned short* __restrict__ value,
    const float* __restrict__ off,
    const float* __restrict__ awlog,
    const float* __restrict__ refp,
    const int* __restrict__ shapes,
    unsigned short* __restrict__ out) {
  int g = blockIdx.x * 64 + (threadIdx.x >> 2);
  int d8 = threadIdx.x & 3;
  int h = g & 7;
  int row = g >> 3;
  int b = row / NQ_DIM;

  const float* lg = awlog + (size_t)row * 128 + h * 16;
  float aw16[16];
  float mx = -1e30f;
#pragma unroll
  for (int i = 0; i < 4; ++i) {
    float4 v = *reinterpret_cast<const float4*>(lg + i * 4);
    aw16[i * 4 + 0] = v.x; aw16[i * 4 + 1] = v.y;
    aw16[i * 4 + 2] = v.z; aw16[i * 4 + 3] = v.w;
  }
#pragma unroll
  for (int i = 0; i < 16; ++i) mx = fmaxf(mx, aw16[i]);
  float ssum = 0.f;
#pragma unroll
  for (int i = 0; i < 16; ++i) { aw16[i] = __expf(aw16[i] - mx); ssum += aw16[i]; }
  float sinv = 1.f / ssum;

  float acc[8] = {};
  int start = 0;
  const float* offr = off + (size_t)row * 256 + h * 32;
  const float* rpr  = refp + (size_t)row * NLVL * 2;
#pragma unroll
  for (int l = 0; l < NLVL; ++l) {
    int Hl = shapes[2 * l], Wl = shapes[2 * l + 1];
    float fx = rpr[2 * l + 0] * (float)Wl - 0.5f;
    float fy = rpr[2 * l + 1] * (float)Hl - 0.5f;
    const unsigned short* vbase =
        value + ((size_t)(b * LEN_DIM + start)) * C_DIM + h * HDIM + d8 * 8;
#pragma unroll
    for (int p = 0; p < NPT; ++p) {
      float x = fx + offr[l * 8 + p * 2];
      float y = fy + offr[l * 8 + p * 2 + 1];
      float a = aw16[l * 4 + p] * sinv;
      float x0f = floorf(x), y0f = floorf(y);
      float dx = x - x0f, dy = y - y0f;
      int x0 = (int)x0f, y0 = (int)y0f;
      int x1 = x0 + 1, y1 = y0 + 1;
      float wx1 = dx, wx0 = 1.f - dx;
      float wy1 = dy * a, wy0 = (1.f - dy) * a;
      bool vx0 = ((unsigned)x0 < (unsigned)Wl);
      bool vx1 = ((unsigned)x1 < (unsigned)Wl);
      bool vy0 = ((unsigned)y0 < (unsigned)Hl);
      bool vy1 = ((unsigned)y1 < (unsigned)Hl);
      float w00 = (vx0 && vy0) ? wx0 * wy0 : 0.f;
      float w10 = (vx1 && vy0) ? wx1 * wy0 : 0.f;
      float w01 = (vx0 && vy1) ? wx0 * wy1 : 0.f;
      float w11 = (vx1 && vy1) ? wx1 * wy1 : 0.f;
      int x0c = min(max(x0, 0), Wl - 1), x1c = min(max(x1, 0), Wl - 1);
      int y0c = min(max(y0, 0), Hl - 1), y1c = min(max(y1, 0), Hl - 1);
      int r0 = y0c * Wl, r1 = y1c * Wl;
      ushort8v g00 = *reinterpret_cast<const ushort8v*>(vbase + ((r0 + x0c) << 8));
      ushort8v g10 = *reinterpret_cast<const ushort8v*>(vbase + ((r0 + x1c) << 8));
      ushort8v g01 = *reinterpret_cast<const ushort8v*>(vbase + ((r1 + x0c) << 8));
      ushort8v g11 = *reinterpret_cast<const ushort8v*>(vbase + ((r1 + x1c) << 8));
#pragma unroll
      for (int j = 0; j < 8; ++j)
        acc[j] += w00 * bf2f(g00[j]) + w10 * bf2f(g10[j]) +
                  w01 * bf2f(g01[j]) + w11 * bf2f(g11[j]);
    }
    start += Hl * Wl;
  }
  ushort8v o;
#pragma unroll
  for (int j = 0; j < 8; ++j) o[j] = f2bf(acc[j]);
  *reinterpret_cast<ushort8v*>(out + (size_t)row * C_DIM + h * HDIM + d8 * 8) = o;
}

// =====================================================================
extern "C" void kernel_launch(void* const* d_in, const int* in_sizes, int n_in,
                              void* d_out, int out_size, void* d_ws, size_t ws_size,
                              hipStream_t stream) {
  const float* tgt      = (const float*)d_in[0];
  const float* qpos     = (const float*)d_in[1];
  const float* refp     = (const float*)d_in[2];
  const float* src      = (const float*)d_in[3];
  const int*   shapes   = (const int*)d_in[4];
  const float* sa_in_w  = (const float*)d_in[5];
  const float* sa_in_b  = (const float*)d_in[6];
  const float* sa_out_w = (const float*)d_in[7];
  const float* sa_out_b = (const float*)d_in[8];
  const float* ln2_g    = (const float*)d_in[9];
  const float* ln2_b    = (const float*)d_in[10];
  const float* off_w    = (const float*)d_in[11];
  const float* off_b    = (const float*)d_in[12];
  const float* attw_w   = (const float*)d_in[13];
  const float* attw_b   = (const float*)d_in[14];
  const float* val_w    = (const float*)d_in[15];
  const float* val_b    = (const float*)d_in[16];
  const float* proj_w   = (const float*)d_in[17];
  const float* proj_b   = (const float*)d_in[18];
  const float* ln1_g    = (const float*)d_in[19];
  const float* ln1_b    = (const float*)d_in[20];
  const float* lin1_w   = (const float*)d_in[21];
  const float* lin1_b   = (const float*)d_in[22];
  const float* lin2_w   = (const float*)d_in[23];
  const float* lin2_b   = (const float*)d_in[24];
  const float* ln3_g    = (const float*)d_in[25];
  const float* ln3_b    = (const float*)d_in[26];

  char* ws = (char*)d_ws;
  size_t off_b_ws = 0;
  auto alloc = [&](size_t bytes) {
    char* p = ws + off_b_ws;
    off_b_ws += (bytes + 255) & ~(size_t)255;
    return p;
  };
  unsigned short* wT     = (unsigned short*)alloc((size_t)1015808 * 2);
  unsigned short* value  = (unsigned short*)alloc((size_t)VROWS * C_DIM * 2);
  unsigned short* qkbuf  = (unsigned short*)alloc((size_t)ROWS * 512 * 2);
  unsigned short* vbuf   = (unsigned short*)alloc((size_t)ROWS * 256 * 2);
  unsigned short* vTbuf  = (unsigned short*)alloc((size_t)BB * 256 * VT_LD * 2);
  unsigned short* tgtbf  = (unsigned short*)alloc((size_t)ROWS * C_DIM * 2);
  unsigned short* X0bf   = (unsigned short*)alloc((size_t)ROWS * C_DIM * 2);
  unsigned short* attnbf = (unsigned short*)alloc((size_t)ROWS * C_DIM * 2);
  unsigned short* X3bf   = (unsigned short*)alloc((size_t)ROWS * C_DIM * 2);
  unsigned short* sampbf = (unsigned short*)alloc((size_t)ROWS * C_DIM * 2);
  unsigned short* X6bf   = (unsigned short*)alloc((size_t)ROWS * C_DIM * 2);
  unsigned short* hidbf  = (unsigned short*)alloc((size_t)ROWS * DFF_DIM * 2);
  float* X1 = (float*)alloc((size_t)ROWS * C_DIM * 4);
  float* X2 = (float*)alloc((size_t)ROWS * C_DIM * 4);
  float* X4 = (float*)alloc((size_t)ROWS * C_DIM * 4);
  float* X5 = (float*)alloc((size_t)ROWS * 128 * 4);
  float* X6 = (float*)alloc((size_t)ROWS * C_DIM * 4);
  if (off_b_ws > ws_size) return;

  // wT segment offsets (order must match wprep_kernel)
  unsigned short* sa_inT = wT + 0;        // [768][256]
  unsigned short* sa_outT = wT + 196608;  // [256][256]
  unsigned short* offT   = wT + 262144;   // [256][256] (attwT contiguous after)
  unsigned short* valT   = wT + 360448;
  unsigned short* projT  = wT + 425984;
  unsigned short* lin1T  = wT + 491520;   // [1024][256]
  unsigned short* lin2T  = wT + 753664;   // [256][1024]

  dim3 blk(256);
  const int MBV = (VROWS + 127) / 128;        // 831
  const int MB64 = (ROWS + 63) / 64;          // 113
  int n4 = ROWS * C_DIM / 4;
  int prepBlocks = (n4 + 255) / 256;
  const int lnBlocks = ROWS / 4;              // 1800

  // ---- merged weight-transpose + bf16 prep ----
  wprep_kernel<<<WCONV_BLOCKS + prepBlocks, blk, 0, stream>>>(
      sa_in_w, sa_out_w, off_w, attw_w, val_w, proj_w, lin1_w, lin2_w, wT,
      tgt, qpos, tgtbf, X0bf, n4);

  // ---- fused qkv GEMM + value GEMM (BK=64) ----
  qkv_value_kernel<<<QKV_BLOCKS + 2 * MBV, blk, 0, stream>>>(
      X0bf, tgtbf, sa_inT, sa_in_b, (__hip_bfloat16*)qkbuf, (__hip_bfloat16*)vbuf,
      src, valT, val_b, (__hip_bfloat16*)value);

  // ---- V transpose ----
  vtrans_kernel<<<dim3(8 * 29, BB), blk, 0, stream>>>(vbuf, vTbuf);

  // ---- self-attention ----
  self_attn_mfma_kernel<<<dim3(15, 64), blk, 0, stream>>>(qkbuf, vTbuf, attnbf);

  // ---- self-attn out proj + LN2 ----
  mfma_gemm64_kernel<unsigned short, float, 0><<<dim3(4, MB64), blk, 0, stream>>>(
      attnbf, nullptr, sa_outT, sa_out_b, nullptr,
      X1, nullptr, ROWS, 256, 256, 256, 256, 0, 1 << 30);
  ln_fused_kernel<<<lnBlocks, blk, 0, stream>>>(tgt, X1, ln2_g, ln2_b, X2, X3bf, qpos);

  // ---- MSDeformAttn ----
  mfma_gemm64_kernel<unsigned short, float, 0><<<dim3(6, MB64), blk, 0, stream>>>(
      X3bf, nullptr, offT, off_b, attw_b,
      X4, X5, ROWS, 384, 256, 256, 256, 128, 256);
  msda_sample_kernel<<<ROWS * NHEAD / 64, blk, 0, stream>>>(
      value, X4, X5, refp, shapes, sampbf);
  mfma_gemm64_kernel<unsigned short, float, 0><<<dim3(4, MB64), blk, 0, stream>>>(
      sampbf, nullptr, projT, proj_b, nullptr,
      X1, nullptr, ROWS, 256, 256, 256, 256, 0, 1 << 30);
  ln_fused_kernel<<<lnBlocks, blk, 0, stream>>>(X2, X1, ln1_g, ln1_b, X6, X6bf, nullptr);

  // ---- FFN ----
  mfma_gemm64_kernel<unsigned short, __hip_bfloat16, 1><<<dim3(16, MB64), blk, 0, stream>>>(
      X6bf, nullptr, lin1T, lin1_b, nullptr,
      (__hip_bfloat16*)hidbf, nullptr, ROWS, 1024, 256, 256, 1024, 0, 1 << 30);
  mfma_gemm64_kernel<unsigned short, float, 0><<<dim3(4, MB64), blk, 0, stream>>>(
      hidbf, nullptr, lin2T, lin2_b, nullptr,
      X1, nullptr, ROWS, 256, 1024, 1024, 256, 0, 1 << 30);
  ln_fused_kernel<<<lnBlocks, blk, 0, stream>>>(X6, X1, ln3_g, ln3_b, (float*)d_out, nullptr, nullptr);
}